// Round 1
// baseline (1170.098 us; speedup 1.0000x reference)
//
#include <hip/hip_runtime.h>
#include <stdint.h>

// Problem constants
// b=4, n=2048, DIM=512, SEARCH=8, HD=64, RETRIEVAL=8, HVD=64
// d_out = [ y: 4*2048*512 | score: 4*8*2048*2048 | v_score: 4*2048*8*8 ] f32

typedef __bf16 bf16;
typedef __attribute__((ext_vector_type(8))) __bf16 bf16x8;
typedef __attribute__((ext_vector_type(4))) float f32x4;

__device__ __forceinline__ bf16 f2bf(float f) {
  unsigned u = __builtin_bit_cast(unsigned, f);
  unsigned r = (u + 0x7FFFu + ((u >> 16) & 1u)) >> 16;
  unsigned short h = (unsigned short)r;
  return __builtin_bit_cast(bf16, h);
}

__device__ __forceinline__ void gload16(const void* g, void* l) {
  __builtin_amdgcn_global_load_lds(
      (const __attribute__((address_space(1))) unsigned int*)g,
      (__attribute__((address_space(3))) unsigned int*)l, 16, 0, 0);
}

// ---------------- conversion kernels ----------------
__global__ __launch_bounds__(256) void k_cvt_x(const float* __restrict__ x,
                                               bf16* __restrict__ xb) {
  long i = ((long)blockIdx.x * 256 + threadIdx.x) * 8;
  float4 a = *(const float4*)(x + i);
  float4 b = *(const float4*)(x + i + 4);
  bf16x8 o;
  o[0] = f2bf(a.x); o[1] = f2bf(a.y); o[2] = f2bf(a.z); o[3] = f2bf(a.w);
  o[4] = f2bf(b.x); o[5] = f2bf(b.y); o[6] = f2bf(b.z); o[7] = f2bf(b.w);
  *(bf16x8*)(xb + i) = o;
}

// WcatT[j][k] = W?[k][j%512] * scale  (j: 0-511 Wq*0.125 | 512-1023 Wk | 1024-1535 Wv | 1536-2047 Wvq*0.125)
__global__ __launch_bounds__(256) void k_cvt_wcat(
    const float* __restrict__ Wq, const float* __restrict__ bq,
    const float* __restrict__ Wk, const float* __restrict__ bk,
    const float* __restrict__ Wv, const float* __restrict__ bv,
    const float* __restrict__ Wvq, const float* __restrict__ bvq,
    bf16* __restrict__ WcatT, float* __restrict__ bcat) {
  int j = blockIdx.x;
  int grp = j >> 9, jc = j & 511;
  const float* W; const float* bb; float sc;
  if (grp == 0)      { W = Wq;  bb = bq;  sc = 0.125f; }
  else if (grp == 1) { W = Wk;  bb = bk;  sc = 1.0f;   }
  else if (grp == 2) { W = Wv;  bb = bv;  sc = 1.0f;   }
  else               { W = Wvq; bb = bvq; sc = 0.125f; }
  for (int k = threadIdx.x; k < 512; k += 256)
    WcatT[j * 512 + k] = f2bf(W[k * 512 + jc] * sc);
  if (threadIdx.x == 0) bcat[j] = bb[jc] * sc;
}

__global__ __launch_bounds__(256) void k_cvt_wo(const float* __restrict__ Wo,
                                                bf16* __restrict__ WoT) {
  int j = blockIdx.x;
  for (int k = threadIdx.x; k < 512; k += 256)
    WoT[j * 512 + k] = f2bf(Wo[k * 512 + j]);
}

// V transpose: vt[b][j][n] = qkvq[b*2048+n][1024+j]
__global__ __launch_bounds__(256) void k_transpose_v(const bf16* __restrict__ qkvq,
                                                     bf16* __restrict__ vt) {
  __shared__ bf16 tile[64][72];
  int bidx = blockIdx.x;
  int ntile = bidx & 31, jt = (bidx >> 5) & 7, b = bidx >> 8;
  int tid = threadIdx.x;
  int r = tid >> 3, c8 = (tid & 7) * 8;
#pragma unroll
  for (int rr = r; rr < 64; rr += 32) {
    const bf16* src = qkvq + (long)(b * 2048 + ntile * 64 + rr) * 2048 + 1024 + jt * 64 + c8;
    bf16x8 v = *(const bf16x8*)src;
#pragma unroll
    for (int e = 0; e < 8; e++) tile[rr][c8 + e] = v[e];
  }
  __syncthreads();
#pragma unroll
  for (int rr = r; rr < 64; rr += 32) {
    bf16x8 v;
#pragma unroll
    for (int e = 0; e < 8; e++) v[e] = tile[c8 + e][rr];
    *(bf16x8*)(vt + ((long)b * 512 + jt * 64 + rr) * 2048 + ntile * 64 + c8) = v;
  }
}

// ---------------- generic bf16 MFMA GEMM: C[M][ldc] = A[M][lda] @ BT[N][ldb]^T + bias ----------------
__device__ __forceinline__ void cstore(float* p, float v) { *p = v; }
__device__ __forceinline__ void cstore(bf16* p, float v) { *p = f2bf(v); }

template <typename CT>
__global__ __launch_bounds__(256) void k_gemm(
    const bf16* __restrict__ A, int lda,
    const bf16* __restrict__ BT, int ldb,
    CT* __restrict__ C, int ldc,
    const float* __restrict__ bias,
    int K, int ntiles) {
  __shared__ bf16 smem[32 * 512];  // 32 slots of 1 KB; A: 0-15, B: 16-31
  int mt = blockIdx.x / ntiles, nt = blockIdx.x % ntiles;
  int tid = threadIdx.x, lane = tid & 63, w = tid >> 6;
  int lr = lane & 15, lq = lane >> 4;
  int wm = w & 1, wn = w >> 1;

  f32x4 acc[4][4];
#pragma unroll
  for (int i = 0; i < 4; i++)
#pragma unroll
    for (int j = 0; j < 4; j++) acc[i][j] = (f32x4){0.f, 0.f, 0.f, 0.f};

  for (int k0 = 0; k0 < K; k0 += 64) {
#pragma unroll
    for (int ss = 0; ss < 8; ss++) {
      int gsl = w * 8 + ss;
      int sl = gsl & 15, g = sl >> 1, t = sl & 1;
      const bf16* src = (gsl < 16)
          ? A + (long)(mt * 128 + g * 16 + lr) * lda + k0 + t * 32 + lq * 8
          : BT + (long)(nt * 128 + g * 16 + lr) * ldb + k0 + t * 32 + lq * 8;
      gload16(src, &smem[gsl * 512]);
    }
    __syncthreads();
#pragma unroll
    for (int t = 0; t < 2; t++) {
      bf16x8 af[4], bfr[4];
#pragma unroll
      for (int i = 0; i < 4; i++)
        af[i] = *(const bf16x8*)&smem[((wm * 4 + i) * 2 + t) * 512 + lane * 8];
#pragma unroll
      for (int j = 0; j < 4; j++)
        bfr[j] = *(const bf16x8*)&smem[(16 + (wn * 4 + j) * 2 + t) * 512 + lane * 8];
#pragma unroll
      for (int i = 0; i < 4; i++)
#pragma unroll
        for (int j = 0; j < 4; j++)
          acc[i][j] = __builtin_amdgcn_mfma_f32_16x16x32_bf16(af[i], bfr[j], acc[i][j], 0, 0, 0);
    }
    __syncthreads();
  }
#pragma unroll
  for (int i = 0; i < 4; i++) {
    int row = mt * 128 + wm * 64 + i * 16 + lq * 4;
#pragma unroll
    for (int j = 0; j < 4; j++) {
      int col = nt * 128 + wn * 64 + j * 16 + lr;
      float bv_ = bias[col];
#pragma unroll
      for (int r = 0; r < 4; r++)
        cstore(C + (long)(row + r) * ldc + col, acc[i][j][r] + bv_);
    }
  }
}

// ---------------- rowsum: rinv[b][s][n] = 1/sum_{m!=n} exp(q_n . k_m) ----------------
__global__ __launch_bounds__(256) void k_rowsum(const bf16* __restrict__ qkvq,
                                                float* __restrict__ rinv) {
  __shared__ bf16 smem[32 * 512];
  int rt = blockIdx.x & 15, s = (blockIdx.x >> 4) & 7, b = blockIdx.x >> 7;
  int tid = threadIdx.x, lane = tid & 63, w = tid >> 6;
  int lr = lane & 15, lq = lane >> 4;
  const bf16* Q = qkvq + (long)b * 2048 * 2048 + s * 64;
  const bf16* Kp = qkvq + (long)b * 2048 * 2048 + 512 + s * 64;

  // stage Q tile once (slots 0-15)
#pragma unroll
  for (int ss = 0; ss < 4; ss++) {
    int sl = w * 4 + ss, g = sl >> 1, t = sl & 1;
    gload16(Q + (long)(rt * 128 + g * 16 + lr) * 2048 + t * 32 + lq * 8, &smem[sl * 512]);
  }
  float racc[2][4];
#pragma unroll
  for (int i = 0; i < 2; i++)
#pragma unroll
    for (int r = 0; r < 4; r++) racc[i][r] = 0.f;

  for (int mt = 0; mt < 16; mt++) {
#pragma unroll
    for (int ss = 0; ss < 4; ss++) {
      int sl = w * 4 + ss, g = sl >> 1, t = sl & 1;
      gload16(Kp + (long)(mt * 128 + g * 16 + lr) * 2048 + t * 32 + lq * 8,
              &smem[(16 + sl) * 512]);
    }
    __syncthreads();
    // wave w computes rows w*32..w*32+31 x all 128 cols (so row-sums stay wave-local)
    f32x4 acc[2][8];
#pragma unroll
    for (int i = 0; i < 2; i++)
#pragma unroll
      for (int j = 0; j < 8; j++) acc[i][j] = (f32x4){0.f, 0.f, 0.f, 0.f};
#pragma unroll
    for (int t = 0; t < 2; t++) {
      bf16x8 af[2], bfr[8];
#pragma unroll
      for (int i = 0; i < 2; i++)
        af[i] = *(const bf16x8*)&smem[((w * 2 + i) * 2 + t) * 512 + lane * 8];
#pragma unroll
      for (int j = 0; j < 8; j++)
        bfr[j] = *(const bf16x8*)&smem[(16 + j * 2 + t) * 512 + lane * 8];
#pragma unroll
      for (int i = 0; i < 2; i++)
#pragma unroll
        for (int j = 0; j < 8; j++)
          acc[i][j] = __builtin_amdgcn_mfma_f32_16x16x32_bf16(af[i], bfr[j], acc[i][j], 0, 0, 0);
    }
#pragma unroll
    for (int i = 0; i < 2; i++) {
      int gnb = rt * 128 + w * 32 + i * 16 + lq * 4;
#pragma unroll
      for (int j = 0; j < 8; j++) {
        int gm = mt * 128 + j * 16 + lr;
#pragma unroll
        for (int r = 0; r < 4; r++) {
          float e = __expf(acc[i][j][r]);
          racc[i][r] += (gm == gnb + r) ? 0.f : e;
        }
      }
    }
    __syncthreads();
  }
#pragma unroll
  for (int i = 0; i < 2; i++)
#pragma unroll
    for (int r = 0; r < 4; r++) {
      float v = racc[i][r];
      v += __shfl_xor(v, 1); v += __shfl_xor(v, 2);
      v += __shfl_xor(v, 4); v += __shfl_xor(v, 8);
      if (lr == 0)
        rinv[(long)(b * 8 + s) * 2048 + rt * 128 + w * 32 + i * 16 + lq * 4 + r] = 1.0f / v;
    }
}

// ---------------- P write: score = exp(S)*rinv, diag=0 ----------------
__global__ __launch_bounds__(256) void k_pwrite(const bf16* __restrict__ qkvq,
                                                const float* __restrict__ rinv,
                                                float* __restrict__ scout) {
  __shared__ bf16 smem[32 * 512];
  __shared__ float rl[128];
  int mt = blockIdx.x & 15, rt = (blockIdx.x >> 4) & 15;
  int s = (blockIdx.x >> 8) & 7, b = blockIdx.x >> 11;
  int tid = threadIdx.x, lane = tid & 63, w = tid >> 6;
  int lr = lane & 15, lq = lane >> 4;
  int wm = w & 1, wn = w >> 1;
  const bf16* Q = qkvq + (long)b * 2048 * 2048 + s * 64;
  const bf16* Kp = qkvq + (long)b * 2048 * 2048 + 512 + s * 64;

#pragma unroll
  for (int ss = 0; ss < 8; ss++) {
    int gsl = w * 8 + ss;
    int sl = gsl & 15, g = sl >> 1, t = sl & 1;
    const bf16* src = (gsl < 16)
        ? Q + (long)(rt * 128 + g * 16 + lr) * 2048 + t * 32 + lq * 8
        : Kp + (long)(mt * 128 + g * 16 + lr) * 2048 + t * 32 + lq * 8;
    gload16(src, &smem[gsl * 512]);
  }
  if (tid < 128) rl[tid] = rinv[(long)(b * 8 + s) * 2048 + rt * 128 + tid];
  __syncthreads();

  f32x4 acc[4][4];
#pragma unroll
  for (int i = 0; i < 4; i++)
#pragma unroll
    for (int j = 0; j < 4; j++) acc[i][j] = (f32x4){0.f, 0.f, 0.f, 0.f};
#pragma unroll
  for (int t = 0; t < 2; t++) {
    bf16x8 af[4], bfr[4];
#pragma unroll
    for (int i = 0; i < 4; i++)
      af[i] = *(const bf16x8*)&smem[((wm * 4 + i) * 2 + t) * 512 + lane * 8];
#pragma unroll
    for (int j = 0; j < 4; j++)
      bfr[j] = *(const bf16x8*)&smem[(16 + (wn * 4 + j) * 2 + t) * 512 + lane * 8];
#pragma unroll
    for (int i = 0; i < 4; i++)
#pragma unroll
      for (int j = 0; j < 4; j++)
        acc[i][j] = __builtin_amdgcn_mfma_f32_16x16x32_bf16(af[i], bfr[j], acc[i][j], 0, 0, 0);
  }
  float* outp = scout + ((long)(b * 8 + s) * 2048 + rt * 128) * 2048 + mt * 128;
#pragma unroll
  for (int i = 0; i < 4; i++) {
    int rowl = wm * 64 + i * 16 + lq * 4;
#pragma unroll
    for (int j = 0; j < 4; j++) {
      int col = wn * 64 + j * 16 + lr;
      int gm = mt * 128 + col;
#pragma unroll
      for (int r = 0; r < 4; r++) {
        int rrow = rowl + r;
        int gn = rt * 128 + rrow;
        float p = (gm == gn) ? 0.f : __expf(acc[i][j][r]) * rl[rrow];
        outp[(long)rrow * 2048 + col] = p;
      }
    }
  }
}

// ---------------- PV: out1[b][s][n][512] = P @ V ----------------
// XCD swizzle: the 4 nt-blocks sharing a P row-panel are consecutive in
// blockIdx; remap so they land on the SAME XCD (private L2) instead of 4
// different ones. 2048 % 8 == 0 -> the simple remap is bijective.
__global__ __launch_bounds__(256) void k_pv(const float* __restrict__ P,
                                            const bf16* __restrict__ vt,
                                            bf16* __restrict__ out1) {
  __shared__ bf16 smem[32 * 512];
  int id = (blockIdx.x & 7) * 256 + (blockIdx.x >> 3);
  int nt = id & 3, mt = (id >> 2) & 15;
  int s = (id >> 6) & 7, b = id >> 9;
  int tid = threadIdx.x, lane = tid & 63, w = tid >> 6;
  int lr = lane & 15, lq = lane >> 4;
  int wm = w & 1, wn = w >> 1;
  const float* Pb = P + (long)(b * 8 + s) * 2048 * 2048;
  const bf16* Vb = vt + (long)b * 512 * 2048;

  f32x4 acc[4][4];
#pragma unroll
  for (int i = 0; i < 4; i++)
#pragma unroll
    for (int j = 0; j < 4; j++) acc[i][j] = (f32x4){0.f, 0.f, 0.f, 0.f};

  for (int k0 = 0; k0 < 2048; k0 += 64) {
#pragma unroll
    for (int ss = 0; ss < 4; ss++) {  // B (V^T) via async
      int sl = w * 4 + ss, g = sl >> 1, t = sl & 1;
      gload16(Vb + (long)(nt * 128 + g * 16 + lr) * 2048 + k0 + t * 32 + lq * 8,
              &smem[(16 + sl) * 512]);
    }
#pragma unroll
    for (int ss = 0; ss < 4; ss++) {  // A (P) manual f32->bf16
      int sl = w * 4 + ss, g = sl >> 1, t = sl & 1;
      const float* src = Pb + (long)(mt * 128 + g * 16 + lr) * 2048 + k0 + t * 32 + lq * 8;
      float4 x0 = *(const float4*)src;
      float4 x1 = *(const float4*)(src + 4);
      bf16x8 o;
      o[0] = f2bf(x0.x); o[1] = f2bf(x0.y); o[2] = f2bf(x0.z); o[3] = f2bf(x0.w);
      o[4] = f2bf(x1.x); o[5] = f2bf(x1.y); o[6] = f2bf(x1.z); o[7] = f2bf(x1.w);
      *(bf16x8*)&smem[sl * 512 + lane * 8] = o;
    }
    __syncthreads();
#pragma unroll
    for (int t = 0; t < 2; t++) {
      bf16x8 af[4], bfr[4];
#pragma unroll
      for (int i = 0; i < 4; i++)
        af[i] = *(const bf16x8*)&smem[((wm * 4 + i) * 2 + t) * 512 + lane * 8];
#pragma unroll
      for (int j = 0; j < 4; j++)
        bfr[j] = *(const bf16x8*)&smem[(16 + (wn * 4 + j) * 2 + t) * 512 + lane * 8];
#pragma unroll
      for (int i = 0; i < 4; i++)
#pragma unroll
        for (int j = 0; j < 4; j++)
          acc[i][j] = __builtin_amdgcn_mfma_f32_16x16x32_bf16(af[i], bfr[j], acc[i][j], 0, 0, 0);
    }
    __syncthreads();
  }
  bf16* Ob = out1 + (long)(b * 8 + s) * 2048 * 512;
#pragma unroll
  for (int i = 0; i < 4; i++) {
    int row = mt * 128 + wm * 64 + i * 16 + lq * 4;
#pragma unroll
    for (int j = 0; j < 4; j++) {
      int col = nt * 128 + wn * 64 + j * 16 + lr;
#pragma unroll
      for (int r = 0; r < 4; r++)
        Ob[(long)(row + r) * 512 + col] = f2bf(acc[i][j][r]);
    }
  }
}

// ---------------- stage 2: gated retrieval selection ----------------
// v_logits[r] = (Wvk @ q_v) . out[r]  (+ const that cancels in softmax)
__global__ __launch_bounds__(256) void k_stage2(const bf16* __restrict__ out1,
                                                const bf16* __restrict__ qkvq,
                                                const float* __restrict__ Wvk,
                                                float* __restrict__ vsout,
                                                bf16* __restrict__ out2) {
  __shared__ float so[8][8][64];   // [s][r][v]
  __shared__ float qvl[4][2][64];
  int b = blockIdx.x >> 11, n = blockIdx.x & 2047;
  int tid = threadIdx.x, w = tid >> 6, lane = tid & 63;

  float wr[64];  // Wvk row `lane`: Wvk[v=lane][h]
#pragma unroll
  for (int c = 0; c < 16; c++) {
    float4 t4 = *(const float4*)(Wvk + lane * 64 + c * 4);
    wr[c * 4 + 0] = t4.x; wr[c * 4 + 1] = t4.y;
    wr[c * 4 + 2] = t4.z; wr[c * 4 + 3] = t4.w;
  }
  for (int c = tid; c < 512; c += 256) {
    int s = c >> 6; int off = (c & 63) * 8;
    bf16x8 v = *(const bf16x8*)(out1 + ((long)(b * 8 + s) * 2048 + n) * 512 + off);
#pragma unroll
    for (int e = 0; e < 8; e++) so[s][(off + e) >> 6][(off + e) & 63] = (float)v[e];
  }
#pragma unroll
  for (int si = 0; si < 2; si++) {
    int s = w * 2 + si;
    qvl[w][si][lane] = (float)qkvq[(long)(b * 2048 + n) * 2048 + 1536 + s * 64 + lane];
  }
  __syncthreads();

#pragma unroll
  for (int si = 0; si < 2; si++) {
    int s = w * 2 + si;
    float qw = 0.f;  // qw[v=lane] = sum_h qv[h]*Wvk[v][h]
#pragma unroll
    for (int c = 0; c < 16; c++) {
      float4 q4 = *(const float4*)&qvl[w][si][c * 4];
      qw += q4.x * wr[c * 4 + 0] + q4.y * wr[c * 4 + 1] +
            q4.z * wr[c * 4 + 2] + q4.w * wr[c * 4 + 3];
    }
    float lg[8], sor[8];
#pragma unroll
    for (int r = 0; r < 8; r++) {
      sor[r] = so[s][r][lane];
      float p = sor[r] * qw;
      p += __shfl_xor(p, 1);  p += __shfl_xor(p, 2);  p += __shfl_xor(p, 4);
      p += __shfl_xor(p, 8);  p += __shfl_xor(p, 16); p += __shfl_xor(p, 32);
      lg[r] = p;
    }
    float mx = lg[0];
#pragma unroll
    for (int r = 1; r < 8; r++) mx = fmaxf(mx, lg[r]);
    float e[8], sum = 0.f;
#pragma unroll
    for (int r = 0; r < 8; r++) { e[r] = __expf(lg[r] - mx); sum += e[r]; }
    float rs = 1.f / sum;
    float myv = 0.f;
#pragma unroll
    for (int r = 0; r < 8; r++) myv = (lane == r) ? e[r] * rs : myv;
    if (lane < 8) vsout[((long)(b * 2048 + n) * 8 + s) * 8 + lane] = myv;
    float o2 = 0.f;
#pragma unroll
    for (int r = 0; r < 8; r++) o2 += e[r] * rs * sor[r];
    out2[(long)(b * 2048 + n) * 512 + s * 64 + lane] = f2bf(o2);
  }
}

// ---------------- launch ----------------
extern "C" void kernel_launch(void* const* d_in, const int* in_sizes, int n_in,
                              void* d_out, int out_size, void* d_ws, size_t ws_size,
                              hipStream_t stream) {
  const float* x   = (const float*)d_in[0];
  const float* Wq  = (const float*)d_in[1];  const float* bq  = (const float*)d_in[2];
  const float* Wk  = (const float*)d_in[3];  const float* bk  = (const float*)d_in[4];
  const float* Wv  = (const float*)d_in[5];  const float* bv  = (const float*)d_in[6];
  const float* Wvq = (const float*)d_in[7];  const float* bvq = (const float*)d_in[8];
  const float* Wvk = (const float*)d_in[9];  const float* bvk = (const float*)d_in[10];
  const float* Wo  = (const float*)d_in[11]; const float* bo  = (const float*)d_in[12];
  (void)bvk; (void)in_sizes; (void)n_in; (void)out_size; (void)ws_size;

  char* ws = (char*)d_ws;
  bf16*  qkvq  = (bf16*)(ws + 0);          // [8192][2048]  (Q|K|V|Qv), q/qv pre-scaled
  bf16*  xb    = (bf16*)(ws + 33554432);   // [8192][512]
  bf16*  wcatT = (bf16*)(ws + 41943040);   // [2048][512]
  bf16*  woT   = (bf16*)(ws + 44040192);   // [512][512]
  float* bcat  = (float*)(ws + 44564480);  // [2048]
  bf16*  vt    = (bf16*)(ws + 44572672);   // [4][512][2048]
  float* rinv  = (float*)(ws + 52961280);  // [4][8][2048]
  bf16*  out1  = (bf16*)(ws + 53223424);   // [4][8][2048][512]
  bf16*  out2  = (bf16*)(ws + 120332288);  // [8192][512]
  // total ws use: 128,720,896 B

  float* y  = (float*)d_out;
  float* sc = y + 4194304;     // [4][8][2048][2048]
  float* vs = y + 138412032;   // [4][2048][8][8]

  k_cvt_x<<<2048, 256, 0, stream>>>(x, xb);
  k_cvt_wcat<<<2048, 256, 0, stream>>>(Wq, bq, Wk, bk, Wv, bv, Wvq, bvq, wcatT, bcat);
  k_cvt_wo<<<512, 256, 0, stream>>>(Wo, woT);
  k_gemm<bf16><<<1024, 256, 0, stream>>>(xb, 512, wcatT, 512, qkvq, 2048, bcat, 512, 16);
  k_transpose_v<<<1024, 256, 0, stream>>>(qkvq, vt);
  k_rowsum<<<512, 256, 0, stream>>>(qkvq, rinv);
  k_pwrite<<<8192, 256, 0, stream>>>(qkvq, rinv, sc);
  k_pv<<<2048, 256, 0, stream>>>(sc, vt, out1);
  k_stage2<<<8192, 256, 0, stream>>>(out1, qkvq, Wvk, vs, out2);
  k_gemm<float><<<256, 256, 0, stream>>>(out2, 512, woT, 512, y, 512, bo, 512, 4);
}

// Round 2
// 1170.097 us; speedup vs baseline: 1.0000x; 1.0000x over previous
//
#include <hip/hip_runtime.h>
#include <stdint.h>

// Problem constants
// b=4, n=2048, DIM=512, SEARCH=8, HD=64, RETRIEVAL=8, HVD=64
// d_out = [ y: 4*2048*512 | score: 4*8*2048*2048 | v_score: 4*2048*8*8 ] f32

typedef __bf16 bf16;
typedef __attribute__((ext_vector_type(8))) __bf16 bf16x8;
typedef __attribute__((ext_vector_type(4))) float f32x4;

__device__ __forceinline__ bf16 f2bf(float f) {
  unsigned u = __builtin_bit_cast(unsigned, f);
  unsigned r = (u + 0x7FFFu + ((u >> 16) & 1u)) >> 16;
  unsigned short h = (unsigned short)r;
  return __builtin_bit_cast(bf16, h);
}

__device__ __forceinline__ void gload16(const void* g, void* l) {
  __builtin_amdgcn_global_load_lds(
      (const __attribute__((address_space(1))) unsigned int*)g,
      (__attribute__((address_space(3))) unsigned int*)l, 16, 0, 0);
}

// ---------------- conversion kernels ----------------
__global__ __launch_bounds__(256) void k_cvt_x(const float* __restrict__ x,
                                               bf16* __restrict__ xb) {
  long i = ((long)blockIdx.x * 256 + threadIdx.x) * 8;
  float4 a = *(const float4*)(x + i);
  float4 b = *(const float4*)(x + i + 4);
  bf16x8 o;
  o[0] = f2bf(a.x); o[1] = f2bf(a.y); o[2] = f2bf(a.z); o[3] = f2bf(a.w);
  o[4] = f2bf(b.x); o[5] = f2bf(b.y); o[6] = f2bf(b.z); o[7] = f2bf(b.w);
  *(bf16x8*)(xb + i) = o;
}

// WcatT[j][k] = W?[k][j%512] * scale  (j: 0-511 Wq*0.125 | 512-1023 Wk | 1024-1535 Wv | 1536-2047 Wvq*0.125)
__global__ __launch_bounds__(256) void k_cvt_wcat(
    const float* __restrict__ Wq, const float* __restrict__ bq,
    const float* __restrict__ Wk, const float* __restrict__ bk,
    const float* __restrict__ Wv, const float* __restrict__ bv,
    const float* __restrict__ Wvq, const float* __restrict__ bvq,
    bf16* __restrict__ WcatT, float* __restrict__ bcat) {
  int j = blockIdx.x;
  int grp = j >> 9, jc = j & 511;
  const float* W; const float* bb; float sc;
  if (grp == 0)      { W = Wq;  bb = bq;  sc = 0.125f; }
  else if (grp == 1) { W = Wk;  bb = bk;  sc = 1.0f;   }
  else if (grp == 2) { W = Wv;  bb = bv;  sc = 1.0f;   }
  else               { W = Wvq; bb = bvq; sc = 0.125f; }
  for (int k = threadIdx.x; k < 512; k += 256)
    WcatT[j * 512 + k] = f2bf(W[k * 512 + jc] * sc);
  if (threadIdx.x == 0) bcat[j] = bb[jc] * sc;
}

__global__ __launch_bounds__(256) void k_cvt_wo(const float* __restrict__ Wo,
                                                bf16* __restrict__ WoT) {
  int j = blockIdx.x;
  for (int k = threadIdx.x; k < 512; k += 256)
    WoT[j * 512 + k] = f2bf(Wo[k * 512 + j]);
}

// V transpose: vt[b][j][n] = qkvq[b*2048+n][1024+j]
__global__ __launch_bounds__(256) void k_transpose_v(const bf16* __restrict__ qkvq,
                                                     bf16* __restrict__ vt) {
  __shared__ bf16 tile[64][72];
  int bidx = blockIdx.x;
  int ntile = bidx & 31, jt = (bidx >> 5) & 7, b = bidx >> 8;
  int tid = threadIdx.x;
  int r = tid >> 3, c8 = (tid & 7) * 8;
#pragma unroll
  for (int rr = r; rr < 64; rr += 32) {
    const bf16* src = qkvq + (long)(b * 2048 + ntile * 64 + rr) * 2048 + 1024 + jt * 64 + c8;
    bf16x8 v = *(const bf16x8*)src;
#pragma unroll
    for (int e = 0; e < 8; e++) tile[rr][c8 + e] = v[e];
  }
  __syncthreads();
#pragma unroll
  for (int rr = r; rr < 64; rr += 32) {
    bf16x8 v;
#pragma unroll
    for (int e = 0; e < 8; e++) v[e] = tile[c8 + e][rr];
    *(bf16x8*)(vt + ((long)b * 512 + jt * 64 + rr) * 2048 + ntile * 64 + c8) = v;
  }
}

// ---------------- generic bf16 MFMA GEMM: C[M][ldc] = A[M][lda] @ BT[N][ldb]^T + bias ----------------
__device__ __forceinline__ void cstore(float* p, float v) { *p = v; }
__device__ __forceinline__ void cstore(bf16* p, float v) { *p = f2bf(v); }

template <typename CT>
__global__ __launch_bounds__(256) void k_gemm(
    const bf16* __restrict__ A, int lda,
    const bf16* __restrict__ BT, int ldb,
    CT* __restrict__ C, int ldc,
    const float* __restrict__ bias,
    int K, int ntiles) {
  __shared__ bf16 smem[32 * 512];  // 32 slots of 1 KB; A: 0-15, B: 16-31
  int mt = blockIdx.x / ntiles, nt = blockIdx.x % ntiles;
  int tid = threadIdx.x, lane = tid & 63, w = tid >> 6;
  int lr = lane & 15, lq = lane >> 4;
  int wm = w & 1, wn = w >> 1;

  f32x4 acc[4][4];
#pragma unroll
  for (int i = 0; i < 4; i++)
#pragma unroll
    for (int j = 0; j < 4; j++) acc[i][j] = (f32x4){0.f, 0.f, 0.f, 0.f};

  for (int k0 = 0; k0 < K; k0 += 64) {
#pragma unroll
    for (int ss = 0; ss < 8; ss++) {
      int gsl = w * 8 + ss;
      int sl = gsl & 15, g = sl >> 1, t = sl & 1;
      const bf16* src = (gsl < 16)
          ? A + (long)(mt * 128 + g * 16 + lr) * lda + k0 + t * 32 + lq * 8
          : BT + (long)(nt * 128 + g * 16 + lr) * ldb + k0 + t * 32 + lq * 8;
      gload16(src, &smem[gsl * 512]);
    }
    __syncthreads();
#pragma unroll
    for (int t = 0; t < 2; t++) {
      bf16x8 af[4], bfr[4];
#pragma unroll
      for (int i = 0; i < 4; i++)
        af[i] = *(const bf16x8*)&smem[((wm * 4 + i) * 2 + t) * 512 + lane * 8];
#pragma unroll
      for (int j = 0; j < 4; j++)
        bfr[j] = *(const bf16x8*)&smem[(16 + (wn * 4 + j) * 2 + t) * 512 + lane * 8];
#pragma unroll
      for (int i = 0; i < 4; i++)
#pragma unroll
        for (int j = 0; j < 4; j++)
          acc[i][j] = __builtin_amdgcn_mfma_f32_16x16x32_bf16(af[i], bfr[j], acc[i][j], 0, 0, 0);
    }
    __syncthreads();
  }
#pragma unroll
  for (int i = 0; i < 4; i++) {
    int row = mt * 128 + wm * 64 + i * 16 + lq * 4;
#pragma unroll
    for (int j = 0; j < 4; j++) {
      int col = nt * 128 + wn * 64 + j * 16 + lr;
      float bv_ = bias[col];
#pragma unroll
      for (int r = 0; r < 4; r++)
        cstore(C + (long)(row + r) * ldc + col, acc[i][j][r] + bv_);
    }
  }
}

// ---------------- rowsum: rinv[b][s][n] = 1/sum_{m!=n} exp(q_n . k_m) ----------------
__global__ __launch_bounds__(256) void k_rowsum(const bf16* __restrict__ qkvq,
                                                float* __restrict__ rinv) {
  __shared__ bf16 smem[32 * 512];
  int rt = blockIdx.x & 15, s = (blockIdx.x >> 4) & 7, b = blockIdx.x >> 7;
  int tid = threadIdx.x, lane = tid & 63, w = tid >> 6;
  int lr = lane & 15, lq = lane >> 4;
  const bf16* Q = qkvq + (long)b * 2048 * 2048 + s * 64;
  const bf16* Kp = qkvq + (long)b * 2048 * 2048 + 512 + s * 64;

  // stage Q tile once (slots 0-15)
#pragma unroll
  for (int ss = 0; ss < 4; ss++) {
    int sl = w * 4 + ss, g = sl >> 1, t = sl & 1;
    gload16(Q + (long)(rt * 128 + g * 16 + lr) * 2048 + t * 32 + lq * 8, &smem[sl * 512]);
  }
  float racc[2][4];
#pragma unroll
  for (int i = 0; i < 2; i++)
#pragma unroll
    for (int r = 0; r < 4; r++) racc[i][r] = 0.f;

  for (int mt = 0; mt < 16; mt++) {
#pragma unroll
    for (int ss = 0; ss < 4; ss++) {
      int sl = w * 4 + ss, g = sl >> 1, t = sl & 1;
      gload16(Kp + (long)(mt * 128 + g * 16 + lr) * 2048 + t * 32 + lq * 8,
              &smem[(16 + sl) * 512]);
    }
    __syncthreads();
    // wave w computes rows w*32..w*32+31 x all 128 cols (so row-sums stay wave-local)
    f32x4 acc[2][8];
#pragma unroll
    for (int i = 0; i < 2; i++)
#pragma unroll
      for (int j = 0; j < 8; j++) acc[i][j] = (f32x4){0.f, 0.f, 0.f, 0.f};
#pragma unroll
    for (int t = 0; t < 2; t++) {
      bf16x8 af[2], bfr[8];
#pragma unroll
      for (int i = 0; i < 2; i++)
        af[i] = *(const bf16x8*)&smem[((w * 2 + i) * 2 + t) * 512 + lane * 8];
#pragma unroll
      for (int j = 0; j < 8; j++)
        bfr[j] = *(const bf16x8*)&smem[(16 + j * 2 + t) * 512 + lane * 8];
#pragma unroll
      for (int i = 0; i < 2; i++)
#pragma unroll
        for (int j = 0; j < 8; j++)
          acc[i][j] = __builtin_amdgcn_mfma_f32_16x16x32_bf16(af[i], bfr[j], acc[i][j], 0, 0, 0);
    }
#pragma unroll
    for (int i = 0; i < 2; i++) {
      int gnb = rt * 128 + w * 32 + i * 16 + lq * 4;
#pragma unroll
      for (int j = 0; j < 8; j++) {
        int gm = mt * 128 + j * 16 + lr;
#pragma unroll
        for (int r = 0; r < 4; r++) {
          float e = __expf(acc[i][j][r]);
          racc[i][r] += (gm == gnb + r) ? 0.f : e;
        }
      }
    }
    __syncthreads();
  }
#pragma unroll
  for (int i = 0; i < 2; i++)
#pragma unroll
    for (int r = 0; r < 4; r++) {
      float v = racc[i][r];
      v += __shfl_xor(v, 1); v += __shfl_xor(v, 2);
      v += __shfl_xor(v, 4); v += __shfl_xor(v, 8);
      if (lr == 0)
        rinv[(long)(b * 8 + s) * 2048 + rt * 128 + w * 32 + i * 16 + lq * 4 + r] = 1.0f / v;
    }
}

// ---------------- P write: score = exp(S)*rinv, diag=0 (+ optional bf16 P copy) ----------------
__global__ __launch_bounds__(256) void k_pwrite(const bf16* __restrict__ qkvq,
                                                const float* __restrict__ rinv,
                                                float* __restrict__ scout,
                                                bf16* __restrict__ pb) {
  __shared__ bf16 smem[32 * 512];
  __shared__ float rl[128];
  int mt = blockIdx.x & 15, rt = (blockIdx.x >> 4) & 15;
  int s = (blockIdx.x >> 8) & 7, b = blockIdx.x >> 11;
  int tid = threadIdx.x, lane = tid & 63, w = tid >> 6;
  int lr = lane & 15, lq = lane >> 4;
  int wm = w & 1, wn = w >> 1;
  const bf16* Q = qkvq + (long)b * 2048 * 2048 + s * 64;
  const bf16* Kp = qkvq + (long)b * 2048 * 2048 + 512 + s * 64;

#pragma unroll
  for (int ss = 0; ss < 8; ss++) {
    int gsl = w * 8 + ss;
    int sl = gsl & 15, g = sl >> 1, t = sl & 1;
    const bf16* src = (gsl < 16)
        ? Q + (long)(rt * 128 + g * 16 + lr) * 2048 + t * 32 + lq * 8
        : Kp + (long)(mt * 128 + g * 16 + lr) * 2048 + t * 32 + lq * 8;
    gload16(src, &smem[gsl * 512]);
  }
  if (tid < 128) rl[tid] = rinv[(long)(b * 8 + s) * 2048 + rt * 128 + tid];
  __syncthreads();

  f32x4 acc[4][4];
#pragma unroll
  for (int i = 0; i < 4; i++)
#pragma unroll
    for (int j = 0; j < 4; j++) acc[i][j] = (f32x4){0.f, 0.f, 0.f, 0.f};
#pragma unroll
  for (int t = 0; t < 2; t++) {
    bf16x8 af[4], bfr[4];
#pragma unroll
    for (int i = 0; i < 4; i++)
      af[i] = *(const bf16x8*)&smem[((wm * 4 + i) * 2 + t) * 512 + lane * 8];
#pragma unroll
    for (int j = 0; j < 4; j++)
      bfr[j] = *(const bf16x8*)&smem[(16 + (wn * 4 + j) * 2 + t) * 512 + lane * 8];
#pragma unroll
    for (int i = 0; i < 4; i++)
#pragma unroll
      for (int j = 0; j < 4; j++)
        acc[i][j] = __builtin_amdgcn_mfma_f32_16x16x32_bf16(af[i], bfr[j], acc[i][j], 0, 0, 0);
  }
  long pbase = ((long)(b * 8 + s) * 2048 + rt * 128) * 2048 + mt * 128;
  float* outp = scout + pbase;
  bf16* pbp = pb ? pb + pbase : (bf16*)0;
#pragma unroll
  for (int i = 0; i < 4; i++) {
    int rowl = wm * 64 + i * 16 + lq * 4;
#pragma unroll
    for (int j = 0; j < 4; j++) {
      int col = wn * 64 + j * 16 + lr;
      int gm = mt * 128 + col;
#pragma unroll
      for (int r = 0; r < 4; r++) {
        int rrow = rowl + r;
        int gn = rt * 128 + rrow;
        float p = (gm == gn) ? 0.f : __expf(acc[i][j][r]) * rl[rrow];
        outp[(long)rrow * 2048 + col] = p;
        if (pbp) pbp[(long)rrow * 2048 + col] = f2bf(p);
      }
    }
  }
}

// ---------------- PV (bf16 P): out1[b][s][n][512] = P @ V ----------------
// Pure dual-global_load_lds bf16 GEMM (verified m97 structure) + XCD swizzle.
__global__ __launch_bounds__(256) void k_pv_bf(const bf16* __restrict__ Pb,
                                               const bf16* __restrict__ vt,
                                               bf16* __restrict__ out1) {
  __shared__ bf16 smem[32 * 512];
  int id = (blockIdx.x & 7) * 256 + (blockIdx.x >> 3);
  int nt = id & 3, mt = (id >> 2) & 15;
  int s = (id >> 6) & 7, b = id >> 9;
  int tid = threadIdx.x, lane = tid & 63, w = tid >> 6;
  int lr = lane & 15, lq = lane >> 4;
  int wm = w & 1, wn = w >> 1;
  const bf16* A = Pb + (long)(b * 8 + s) * 2048 * 2048;
  const bf16* BT = vt + (long)b * 512 * 2048;

  f32x4 acc[4][4];
#pragma unroll
  for (int i = 0; i < 4; i++)
#pragma unroll
    for (int j = 0; j < 4; j++) acc[i][j] = (f32x4){0.f, 0.f, 0.f, 0.f};

  for (int k0 = 0; k0 < 2048; k0 += 64) {
#pragma unroll
    for (int ss = 0; ss < 8; ss++) {
      int gsl = w * 8 + ss;
      int sl = gsl & 15, g = sl >> 1, t = sl & 1;
      const bf16* src = (gsl < 16)
          ? A + (long)(mt * 128 + g * 16 + lr) * 2048 + k0 + t * 32 + lq * 8
          : BT + (long)(nt * 128 + g * 16 + lr) * 2048 + k0 + t * 32 + lq * 8;
      gload16(src, &smem[gsl * 512]);
    }
    __syncthreads();
#pragma unroll
    for (int t = 0; t < 2; t++) {
      bf16x8 af[4], bfr[4];
#pragma unroll
      for (int i = 0; i < 4; i++)
        af[i] = *(const bf16x8*)&smem[((wm * 4 + i) * 2 + t) * 512 + lane * 8];
#pragma unroll
      for (int j = 0; j < 4; j++)
        bfr[j] = *(const bf16x8*)&smem[(16 + (wn * 4 + j) * 2 + t) * 512 + lane * 8];
#pragma unroll
      for (int i = 0; i < 4; i++)
#pragma unroll
        for (int j = 0; j < 4; j++)
          acc[i][j] = __builtin_amdgcn_mfma_f32_16x16x32_bf16(af[i], bfr[j], acc[i][j], 0, 0, 0);
    }
    __syncthreads();
  }
  bf16* Ob = out1 + (long)(b * 8 + s) * 2048 * 512;
#pragma unroll
  for (int i = 0; i < 4; i++) {
    int row = mt * 128 + wm * 64 + i * 16 + lq * 4;
#pragma unroll
    for (int j = 0; j < 4; j++) {
      int col = nt * 128 + wn * 64 + j * 16 + lr;
#pragma unroll
      for (int r = 0; r < 4; r++)
        Ob[(long)(row + r) * 512 + col] = f2bf(acc[i][j][r]);
    }
  }
}

// ---------------- PV fallback (f32 P from score output, reg-staged cvt) ----------------
__global__ __launch_bounds__(256) void k_pv(const float* __restrict__ P,
                                            const bf16* __restrict__ vt,
                                            bf16* __restrict__ out1) {
  __shared__ bf16 smem[32 * 512];
  int id = (blockIdx.x & 7) * 256 + (blockIdx.x >> 3);
  int nt = id & 3, mt = (id >> 2) & 15;
  int s = (id >> 6) & 7, b = id >> 9;
  int tid = threadIdx.x, lane = tid & 63, w = tid >> 6;
  int lr = lane & 15, lq = lane >> 4;
  int wm = w & 1, wn = w >> 1;
  const float* Pb = P + (long)(b * 8 + s) * 2048 * 2048;
  const bf16* Vb = vt + (long)b * 512 * 2048;

  f32x4 acc[4][4];
#pragma unroll
  for (int i = 0; i < 4; i++)
#pragma unroll
    for (int j = 0; j < 4; j++) acc[i][j] = (f32x4){0.f, 0.f, 0.f, 0.f};

  for (int k0 = 0; k0 < 2048; k0 += 64) {
#pragma unroll
    for (int ss = 0; ss < 4; ss++) {  // B (V^T) via async
      int sl = w * 4 + ss, g = sl >> 1, t = sl & 1;
      gload16(Vb + (long)(nt * 128 + g * 16 + lr) * 2048 + k0 + t * 32 + lq * 8,
              &smem[(16 + sl) * 512]);
    }
#pragma unroll
    for (int ss = 0; ss < 4; ss++) {  // A (P) manual f32->bf16
      int sl = w * 4 + ss, g = sl >> 1, t = sl & 1;
      const float* src = Pb + (long)(mt * 128 + g * 16 + lr) * 2048 + k0 + t * 32 + lq * 8;
      float4 x0 = *(const float4*)src;
      float4 x1 = *(const float4*)(src + 4);
      bf16x8 o;
      o[0] = f2bf(x0.x); o[1] = f2bf(x0.y); o[2] = f2bf(x0.z); o[3] = f2bf(x0.w);
      o[4] = f2bf(x1.x); o[5] = f2bf(x1.y); o[6] = f2bf(x1.z); o[7] = f2bf(x1.w);
      *(bf16x8*)&smem[sl * 512 + lane * 8] = o;
    }
    __syncthreads();
#pragma unroll
    for (int t = 0; t < 2; t++) {
      bf16x8 af[4], bfr[4];
#pragma unroll
      for (int i = 0; i < 4; i++)
        af[i] = *(const bf16x8*)&smem[((wm * 4 + i) * 2 + t) * 512 + lane * 8];
#pragma unroll
      for (int j = 0; j < 4; j++)
        bfr[j] = *(const bf16x8*)&smem[(16 + (wn * 4 + j) * 2 + t) * 512 + lane * 8];
#pragma unroll
      for (int i = 0; i < 4; i++)
#pragma unroll
        for (int j = 0; j < 4; j++)
          acc[i][j] = __builtin_amdgcn_mfma_f32_16x16x32_bf16(af[i], bfr[j], acc[i][j], 0, 0, 0);
    }
    __syncthreads();
  }
  bf16* Ob = out1 + (long)(b * 8 + s) * 2048 * 512;
#pragma unroll
  for (int i = 0; i < 4; i++) {
    int row = mt * 128 + wm * 64 + i * 16 + lq * 4;
#pragma unroll
    for (int j = 0; j < 4; j++) {
      int col = nt * 128 + wn * 64 + j * 16 + lr;
#pragma unroll
      for (int r = 0; r < 4; r++)
        Ob[(long)(row + r) * 512 + col] = f2bf(acc[i][j][r]);
    }
  }
}

// ---------------- stage 2: gated retrieval selection ----------------
// v_logits[r] = (Wvk @ q_v) . out[r]  (+ const that cancels in softmax)
__global__ __launch_bounds__(256) void k_stage2(const bf16* __restrict__ out1,
                                                const bf16* __restrict__ qkvq,
                                                const float* __restrict__ Wvk,
                                                float* __restrict__ vsout,
                                                bf16* __restrict__ out2) {
  __shared__ float so[8][8][64];   // [s][r][v]
  __shared__ float qvl[4][2][64];
  int b = blockIdx.x >> 11, n = blockIdx.x & 2047;
  int tid = threadIdx.x, w = tid >> 6, lane = tid & 63;

  float wr[64];  // Wvk row `lane`: Wvk[v=lane][h]
#pragma unroll
  for (int c = 0; c < 16; c++) {
    float4 t4 = *(const float4*)(Wvk + lane * 64 + c * 4);
    wr[c * 4 + 0] = t4.x; wr[c * 4 + 1] = t4.y;
    wr[c * 4 + 2] = t4.z; wr[c * 4 + 3] = t4.w;
  }
  for (int c = tid; c < 512; c += 256) {
    int s = c >> 6; int off = (c & 63) * 8;
    bf16x8 v = *(const bf16x8*)(out1 + ((long)(b * 8 + s) * 2048 + n) * 512 + off);
#pragma unroll
    for (int e = 0; e < 8; e++) so[s][(off + e) >> 6][(off + e) & 63] = (float)v[e];
  }
#pragma unroll
  for (int si = 0; si < 2; si++) {
    int s = w * 2 + si;
    qvl[w][si][lane] = (float)qkvq[(long)(b * 2048 + n) * 2048 + 1536 + s * 64 + lane];
  }
  __syncthreads();

#pragma unroll
  for (int si = 0; si < 2; si++) {
    int s = w * 2 + si;
    float qw = 0.f;  // qw[v=lane] = sum_h qv[h]*Wvk[v][h]
#pragma unroll
    for (int c = 0; c < 16; c++) {
      float4 q4 = *(const float4*)&qvl[w][si][c * 4];
      qw += q4.x * wr[c * 4 + 0] + q4.y * wr[c * 4 + 1] +
            q4.z * wr[c * 4 + 2] + q4.w * wr[c * 4 + 3];
    }
    float lg[8], sor[8];
#pragma unroll
    for (int r = 0; r < 8; r++) {
      sor[r] = so[s][r][lane];
      float p = sor[r] * qw;
      p += __shfl_xor(p, 1);  p += __shfl_xor(p, 2);  p += __shfl_xor(p, 4);
      p += __shfl_xor(p, 8);  p += __shfl_xor(p, 16); p += __shfl_xor(p, 32);
      lg[r] = p;
    }
    float mx = lg[0];
#pragma unroll
    for (int r = 1; r < 8; r++) mx = fmaxf(mx, lg[r]);
    float e[8], sum = 0.f;
#pragma unroll
    for (int r = 0; r < 8; r++) { e[r] = __expf(lg[r] - mx); sum += e[r]; }
    float rs = 1.f / sum;
    float myv = 0.f;
#pragma unroll
    for (int r = 0; r < 8; r++) myv = (lane == r) ? e[r] * rs : myv;
    if (lane < 8) vsout[((long)(b * 2048 + n) * 8 + s) * 8 + lane] = myv;
    float o2 = 0.f;
#pragma unroll
    for (int r = 0; r < 8; r++) o2 += e[r] * rs * sor[r];
    out2[(long)(b * 2048 + n) * 512 + s * 64 + lane] = f2bf(o2);
  }
}

// ---------------- launch ----------------
extern "C" void kernel_launch(void* const* d_in, const int* in_sizes, int n_in,
                              void* d_out, int out_size, void* d_ws, size_t ws_size,
                              hipStream_t stream) {
  const float* x   = (const float*)d_in[0];
  const float* Wq  = (const float*)d_in[1];  const float* bq  = (const float*)d_in[2];
  const float* Wk  = (const float*)d_in[3];  const float* bk  = (const float*)d_in[4];
  const float* Wv  = (const float*)d_in[5];  const float* bv  = (const float*)d_in[6];
  const float* Wvq = (const float*)d_in[7];  const float* bvq = (const float*)d_in[8];
  const float* Wvk = (const float*)d_in[9];  const float* bvk = (const float*)d_in[10];
  const float* Wo  = (const float*)d_in[11]; const float* bo  = (const float*)d_in[12];
  (void)bvk; (void)in_sizes; (void)n_in; (void)out_size;

  char* ws = (char*)d_ws;
  bf16*  qkvq  = (bf16*)(ws + 0);          // [8192][2048]  (Q|K|V|Qv), q/qv pre-scaled
  bf16*  xb    = (bf16*)(ws + 33554432);   // [8192][512]
  bf16*  wcatT = (bf16*)(ws + 41943040);   // [2048][512]
  bf16*  woT   = (bf16*)(ws + 44040192);   // [512][512]
  float* bcat  = (float*)(ws + 44564480);  // [2048]
  bf16*  vt    = (bf16*)(ws + 44572672);   // [4][512][2048]
  float* rinv  = (float*)(ws + 52961280);  // [4][8][2048]
  bf16*  out1  = (bf16*)(ws + 53223424);   // [4][8][2048][512]
  bf16*  out2  = (bf16*)(ws + 120332288);  // [8192][512]
  // base ws use: 128,720,896 B; optional bf16 P: +268,435,456 -> 397,156,352
  bool big = ws_size >= 397156352UL;
  bf16* pb = big ? (bf16*)(ws + 128720896) : (bf16*)0;

  float* y  = (float*)d_out;
  float* sc = y + 4194304;     // [4][8][2048][2048]
  float* vs = y + 138412032;   // [4][2048][8][8]

  k_cvt_x<<<2048, 256, 0, stream>>>(x, xb);
  k_cvt_wcat<<<2048, 256, 0, stream>>>(Wq, bq, Wk, bk, Wv, bv, Wvq, bvq, wcatT, bcat);
  k_cvt_wo<<<512, 256, 0, stream>>>(Wo, woT);
  k_gemm<bf16><<<1024, 256, 0, stream>>>(xb, 512, wcatT, 512, qkvq, 2048, bcat, 512, 16);
  k_transpose_v<<<1024, 256, 0, stream>>>(qkvq, vt);
  k_rowsum<<<512, 256, 0, stream>>>(qkvq, rinv);
  k_pwrite<<<8192, 256, 0, stream>>>(qkvq, rinv, sc, pb);
  if (big) k_pv_bf<<<2048, 256, 0, stream>>>(pb, vt, out1);
  else     k_pv<<<2048, 256, 0, stream>>>(sc, vt, out1);
  k_stage2<<<8192, 256, 0, stream>>>(out1, qkvq, Wvk, vs, out2);
  k_gemm<float><<<256, 256, 0, stream>>>(out2, 512, woT, 512, y, 512, bo, 512, 4);
}

// Round 3
// 1103.889 us; speedup vs baseline: 1.0600x; 1.0600x over previous
//
#include <hip/hip_runtime.h>
#include <stdint.h>

// Problem constants
// b=4, n=2048, DIM=512, SEARCH=8, HD=64, RETRIEVAL=8, HVD=64
// d_out = [ y: 4*2048*512 | score: 4*8*2048*2048 | v_score: 4*2048*8*8 ] f32

typedef __bf16 bf16;
typedef __attribute__((ext_vector_type(8))) __bf16 bf16x8;
typedef __attribute__((ext_vector_type(4))) float f32x4;

__device__ __forceinline__ bf16 f2bf(float f) {
  unsigned u = __builtin_bit_cast(unsigned, f);
  unsigned r = (u + 0x7FFFu + ((u >> 16) & 1u)) >> 16;
  unsigned short h = (unsigned short)r;
  return __builtin_bit_cast(bf16, h);
}

__device__ __forceinline__ void gload16(const void* g, void* l) {
  __builtin_amdgcn_global_load_lds(
      (const __attribute__((address_space(1))) unsigned int*)g,
      (__attribute__((address_space(3))) unsigned int*)l, 16, 0, 0);
}

// ---------------- conversion kernels ----------------
__global__ __launch_bounds__(256) void k_cvt_x(const float* __restrict__ x,
                                               bf16* __restrict__ xb) {
  long i = ((long)blockIdx.x * 256 + threadIdx.x) * 8;
  float4 a = *(const float4*)(x + i);
  float4 b = *(const float4*)(x + i + 4);
  bf16x8 o;
  o[0] = f2bf(a.x); o[1] = f2bf(a.y); o[2] = f2bf(a.z); o[3] = f2bf(a.w);
  o[4] = f2bf(b.x); o[5] = f2bf(b.y); o[6] = f2bf(b.z); o[7] = f2bf(b.w);
  *(bf16x8*)(xb + i) = o;
}

// WcatT[j][k] = W?[k][j%512] * scale  (j: 0-511 Wq*0.125 | 512-1023 Wk | 1024-1535 Wv | 1536-2047 Wvq*0.125)
__global__ __launch_bounds__(256) void k_cvt_wcat(
    const float* __restrict__ Wq, const float* __restrict__ bq,
    const float* __restrict__ Wk, const float* __restrict__ bk,
    const float* __restrict__ Wv, const float* __restrict__ bv,
    const float* __restrict__ Wvq, const float* __restrict__ bvq,
    bf16* __restrict__ WcatT, float* __restrict__ bcat) {
  int j = blockIdx.x;
  int grp = j >> 9, jc = j & 511;
  const float* W; const float* bb; float sc;
  if (grp == 0)      { W = Wq;  bb = bq;  sc = 0.125f; }
  else if (grp == 1) { W = Wk;  bb = bk;  sc = 1.0f;   }
  else if (grp == 2) { W = Wv;  bb = bv;  sc = 1.0f;   }
  else               { W = Wvq; bb = bvq; sc = 0.125f; }
  for (int k = threadIdx.x; k < 512; k += 256)
    WcatT[j * 512 + k] = f2bf(W[k * 512 + jc] * sc);
  if (threadIdx.x == 0) bcat[j] = bb[jc] * sc;
}

__global__ __launch_bounds__(256) void k_cvt_wo(const float* __restrict__ Wo,
                                                bf16* __restrict__ WoT) {
  int j = blockIdx.x;
  for (int k = threadIdx.x; k < 512; k += 256)
    WoT[j * 512 + k] = f2bf(Wo[k * 512 + j]);
}

// V transpose: vt[b][j][n] = qkvq[b*2048+n][1024+j]
__global__ __launch_bounds__(256) void k_transpose_v(const bf16* __restrict__ qkvq,
                                                     bf16* __restrict__ vt) {
  __shared__ bf16 tile[64][72];
  int bidx = blockIdx.x;
  int ntile = bidx & 31, jt = (bidx >> 5) & 7, b = bidx >> 8;
  int tid = threadIdx.x;
  int r = tid >> 3, c8 = (tid & 7) * 8;
#pragma unroll
  for (int rr = r; rr < 64; rr += 32) {
    const bf16* src = qkvq + (long)(b * 2048 + ntile * 64 + rr) * 2048 + 1024 + jt * 64 + c8;
    bf16x8 v = *(const bf16x8*)src;
#pragma unroll
    for (int e = 0; e < 8; e++) tile[rr][c8 + e] = v[e];
  }
  __syncthreads();
#pragma unroll
  for (int rr = r; rr < 64; rr += 32) {
    bf16x8 v;
#pragma unroll
    for (int e = 0; e < 8; e++) v[e] = tile[c8 + e][rr];
    *(bf16x8*)(vt + ((long)b * 512 + jt * 64 + rr) * 2048 + ntile * 64 + c8) = v;
  }
}

// ---------------- generic bf16 MFMA GEMM: C[M][ldc] = A[M][lda] @ BT[N][ldb]^T + bias ----------------
__device__ __forceinline__ void cstore(float* p, float v) { *p = v; }
__device__ __forceinline__ void cstore(bf16* p, float v) { *p = f2bf(v); }

template <typename CT>
__global__ __launch_bounds__(256) void k_gemm(
    const bf16* __restrict__ A, int lda,
    const bf16* __restrict__ BT, int ldb,
    CT* __restrict__ C, int ldc,
    const float* __restrict__ bias,
    int K, int ntiles) {
  __shared__ bf16 smem[32 * 512];  // 32 slots of 1 KB; A: 0-15, B: 16-31
  int mt = blockIdx.x / ntiles, nt = blockIdx.x % ntiles;
  int tid = threadIdx.x, lane = tid & 63, w = tid >> 6;
  int lr = lane & 15, lq = lane >> 4;
  int wm = w & 1, wn = w >> 1;

  f32x4 acc[4][4];
#pragma unroll
  for (int i = 0; i < 4; i++)
#pragma unroll
    for (int j = 0; j < 4; j++) acc[i][j] = (f32x4){0.f, 0.f, 0.f, 0.f};

  for (int k0 = 0; k0 < K; k0 += 64) {
#pragma unroll
    for (int ss = 0; ss < 8; ss++) {
      int gsl = w * 8 + ss;
      int sl = gsl & 15, g = sl >> 1, t = sl & 1;
      const bf16* src = (gsl < 16)
          ? A + (long)(mt * 128 + g * 16 + lr) * lda + k0 + t * 32 + lq * 8
          : BT + (long)(nt * 128 + g * 16 + lr) * ldb + k0 + t * 32 + lq * 8;
      gload16(src, &smem[gsl * 512]);
    }
    __syncthreads();
#pragma unroll
    for (int t = 0; t < 2; t++) {
      bf16x8 af[4], bfr[4];
#pragma unroll
      for (int i = 0; i < 4; i++)
        af[i] = *(const bf16x8*)&smem[((wm * 4 + i) * 2 + t) * 512 + lane * 8];
#pragma unroll
      for (int j = 0; j < 4; j++)
        bfr[j] = *(const bf16x8*)&smem[(16 + (wn * 4 + j) * 2 + t) * 512 + lane * 8];
#pragma unroll
      for (int i = 0; i < 4; i++)
#pragma unroll
        for (int j = 0; j < 4; j++)
          acc[i][j] = __builtin_amdgcn_mfma_f32_16x16x32_bf16(af[i], bfr[j], acc[i][j], 0, 0, 0);
    }
    __syncthreads();
  }
#pragma unroll
  for (int i = 0; i < 4; i++) {
    int row = mt * 128 + wm * 64 + i * 16 + lq * 4;
#pragma unroll
    for (int j = 0; j < 4; j++) {
      int col = nt * 128 + wn * 64 + j * 16 + lr;
      float bv_ = bias[col];
#pragma unroll
      for (int r = 0; r < 4; r++)
        cstore(C + (long)(row + r) * ldc + col, acc[i][j][r] + bv_);
    }
  }
}

// ---------------- rowsum: rinv[b][s][n] = 1/sum_{m!=n} exp(q_n . k_m) ----------------
__global__ __launch_bounds__(256) void k_rowsum(const bf16* __restrict__ qkvq,
                                                float* __restrict__ rinv) {
  __shared__ bf16 smem[32 * 512];
  int rt = blockIdx.x & 15, s = (blockIdx.x >> 4) & 7, b = blockIdx.x >> 7;
  int tid = threadIdx.x, lane = tid & 63, w = tid >> 6;
  int lr = lane & 15, lq = lane >> 4;
  const bf16* Q = qkvq + (long)b * 2048 * 2048 + s * 64;
  const bf16* Kp = qkvq + (long)b * 2048 * 2048 + 512 + s * 64;

  // stage Q tile once (slots 0-15)
#pragma unroll
  for (int ss = 0; ss < 4; ss++) {
    int sl = w * 4 + ss, g = sl >> 1, t = sl & 1;
    gload16(Q + (long)(rt * 128 + g * 16 + lr) * 2048 + t * 32 + lq * 8, &smem[sl * 512]);
  }
  float racc[2][4];
#pragma unroll
  for (int i = 0; i < 2; i++)
#pragma unroll
    for (int r = 0; r < 4; r++) racc[i][r] = 0.f;

  for (int mt = 0; mt < 16; mt++) {
#pragma unroll
    for (int ss = 0; ss < 4; ss++) {
      int sl = w * 4 + ss, g = sl >> 1, t = sl & 1;
      gload16(Kp + (long)(mt * 128 + g * 16 + lr) * 2048 + t * 32 + lq * 8,
              &smem[(16 + sl) * 512]);
    }
    __syncthreads();
    // wave w computes rows w*32..w*32+31 x all 128 cols (so row-sums stay wave-local)
    f32x4 acc[2][8];
#pragma unroll
    for (int i = 0; i < 2; i++)
#pragma unroll
      for (int j = 0; j < 8; j++) acc[i][j] = (f32x4){0.f, 0.f, 0.f, 0.f};
#pragma unroll
    for (int t = 0; t < 2; t++) {
      bf16x8 af[2], bfr[8];
#pragma unroll
      for (int i = 0; i < 2; i++)
        af[i] = *(const bf16x8*)&smem[((w * 2 + i) * 2 + t) * 512 + lane * 8];
#pragma unroll
      for (int j = 0; j < 8; j++)
        bfr[j] = *(const bf16x8*)&smem[(16 + j * 2 + t) * 512 + lane * 8];
#pragma unroll
      for (int i = 0; i < 2; i++)
#pragma unroll
        for (int j = 0; j < 8; j++)
          acc[i][j] = __builtin_amdgcn_mfma_f32_16x16x32_bf16(af[i], bfr[j], acc[i][j], 0, 0, 0);
    }
#pragma unroll
    for (int i = 0; i < 2; i++) {
      int gnb = rt * 128 + w * 32 + i * 16 + lq * 4;
#pragma unroll
      for (int j = 0; j < 8; j++) {
        int gm = mt * 128 + j * 16 + lr;
#pragma unroll
        for (int r = 0; r < 4; r++) {
          float e = __expf(acc[i][j][r]);
          racc[i][r] += (gm == gnb + r) ? 0.f : e;
        }
      }
    }
    __syncthreads();
  }
#pragma unroll
  for (int i = 0; i < 2; i++)
#pragma unroll
    for (int r = 0; r < 4; r++) {
      float v = racc[i][r];
      v += __shfl_xor(v, 1); v += __shfl_xor(v, 2);
      v += __shfl_xor(v, 4); v += __shfl_xor(v, 8);
      if (lr == 0)
        rinv[(long)(b * 8 + s) * 2048 + rt * 128 + w * 32 + i * 16 + lq * 4 + r] = 1.0f / v;
    }
}

// ---------------- P write: score = exp(S)*rinv, diag=0 ----------------
__global__ __launch_bounds__(256) void k_pwrite(const bf16* __restrict__ qkvq,
                                                const float* __restrict__ rinv,
                                                float* __restrict__ scout) {
  __shared__ bf16 smem[32 * 512];
  __shared__ float rl[128];
  int mt = blockIdx.x & 15, rt = (blockIdx.x >> 4) & 15;
  int s = (blockIdx.x >> 8) & 7, b = blockIdx.x >> 11;
  int tid = threadIdx.x, lane = tid & 63, w = tid >> 6;
  int lr = lane & 15, lq = lane >> 4;
  int wm = w & 1, wn = w >> 1;
  const bf16* Q = qkvq + (long)b * 2048 * 2048 + s * 64;
  const bf16* Kp = qkvq + (long)b * 2048 * 2048 + 512 + s * 64;

#pragma unroll
  for (int ss = 0; ss < 8; ss++) {
    int gsl = w * 8 + ss;
    int sl = gsl & 15, g = sl >> 1, t = sl & 1;
    const bf16* src = (gsl < 16)
        ? Q + (long)(rt * 128 + g * 16 + lr) * 2048 + t * 32 + lq * 8
        : Kp + (long)(mt * 128 + g * 16 + lr) * 2048 + t * 32 + lq * 8;
    gload16(src, &smem[gsl * 512]);
  }
  if (tid < 128) rl[tid] = rinv[(long)(b * 8 + s) * 2048 + rt * 128 + tid];
  __syncthreads();

  f32x4 acc[4][4];
#pragma unroll
  for (int i = 0; i < 4; i++)
#pragma unroll
    for (int j = 0; j < 4; j++) acc[i][j] = (f32x4){0.f, 0.f, 0.f, 0.f};
#pragma unroll
  for (int t = 0; t < 2; t++) {
    bf16x8 af[4], bfr[4];
#pragma unroll
    for (int i = 0; i < 4; i++)
      af[i] = *(const bf16x8*)&smem[((wm * 4 + i) * 2 + t) * 512 + lane * 8];
#pragma unroll
    for (int j = 0; j < 4; j++)
      bfr[j] = *(const bf16x8*)&smem[(16 + (wn * 4 + j) * 2 + t) * 512 + lane * 8];
#pragma unroll
    for (int i = 0; i < 4; i++)
#pragma unroll
      for (int j = 0; j < 4; j++)
        acc[i][j] = __builtin_amdgcn_mfma_f32_16x16x32_bf16(af[i], bfr[j], acc[i][j], 0, 0, 0);
  }
  float* outp = scout + ((long)(b * 8 + s) * 2048 + rt * 128) * 2048 + mt * 128;
#pragma unroll
  for (int i = 0; i < 4; i++) {
    int rowl = wm * 64 + i * 16 + lq * 4;
#pragma unroll
    for (int j = 0; j < 4; j++) {
      int col = wn * 64 + j * 16 + lr;
      int gm = mt * 128 + col;
#pragma unroll
      for (int r = 0; r < 4; r++) {
        int rrow = rowl + r;
        int gn = rt * 128 + rrow;
        float p = (gm == gn) ? 0.f : __expf(acc[i][j][r]) * rl[rrow];
        outp[(long)rrow * 2048 + col] = p;
      }
    }
  }
}

// ---------------- PV: out1[b][s][n][512] = P @ V ----------------
// P (f32) staged via async global_load_lds in fragment-linear order; f32->bf16
// conversion happens in registers AFTER the async LDS read (off the load
// critical path). No extra workspace needed. XCD swizzle keeps the 4 nt-blocks
// sharing a P row-panel on one XCD L2.
__global__ __launch_bounds__(256) void k_pv(const float* __restrict__ P,
                                            const bf16* __restrict__ vt,
                                            bf16* __restrict__ out1) {
  __shared__ float smemA[64 * 256];  // 32 sub-slots of 1 KB = 32 KB (f32 A tile)
  __shared__ bf16 smemB[16 * 512];   // 16 slots of 1 KB = 16 KB (bf16 B tile)
  int id = (blockIdx.x & 7) * 256 + (blockIdx.x >> 3);
  int nt = id & 3, mt = (id >> 2) & 15;
  int s = (id >> 6) & 7, b = id >> 9;
  int tid = threadIdx.x, lane = tid & 63, w = tid >> 6;
  int lr = lane & 15, lq = lane >> 4;
  int wm = w & 1, wn = w >> 1;
  const float* Pb = P + (long)(b * 8 + s) * 2048 * 2048;
  const bf16* Vb = vt + (long)b * 512 * 2048;

  // per-lane source mapping for f32 A gloads: within a 1 KB sub-slot (u of a
  // 2 KB slot), lane l carries fragment-lane fl = u*32 + (l>>1), half h = l&1.
  int arow_l = (lane >> 1) & 15;              // fl & 15
  int acol_l = ((lane & 1) << 2);             // h*4
  int acol_h = (lane >> 5);                   // (l>>1)>>4

  f32x4 acc[4][4];
#pragma unroll
  for (int i = 0; i < 4; i++)
#pragma unroll
    for (int j = 0; j < 4; j++) acc[i][j] = (f32x4){0.f, 0.f, 0.f, 0.f};

  for (int k0 = 0; k0 < 2048; k0 += 64) {
#pragma unroll
    for (int ss = 0; ss < 4; ss++) {  // B (V^T bf16): 4 wave-gloads
      int sl = w * 4 + ss, g = sl >> 1, t = sl & 1;
      gload16(Vb + (long)(nt * 128 + g * 16 + lr) * 2048 + k0 + t * 32 + lq * 8,
              &smemB[sl * 512]);
    }
#pragma unroll
    for (int ss = 0; ss < 8; ss++) {  // A (P f32): 8 wave-gloads
      int idx = w * 8 + ss;           // 0..31 sub-slots
      int slot = idx >> 1, u = idx & 1;
      int g = slot >> 1, t = slot & 1;
      int row = mt * 128 + g * 16 + arow_l;
      int col = k0 + t * 32 + (u * 2 + acol_h) * 8 + acol_l;
      gload16(Pb + (long)row * 2048 + col, &smemA[idx * 256]);
    }
    __syncthreads();
#pragma unroll
    for (int t = 0; t < 2; t++) {
      bf16x8 af[4], bfr[4];
#pragma unroll
      for (int i = 0; i < 4; i++) {
        int slot = (wm * 4 + i) * 2 + t;
        const float* ap = &smemA[slot * 512 + lane * 8];
        f32x4 a0 = *(const f32x4*)ap;
        f32x4 a1 = *(const f32x4*)(ap + 4);
        bf16x8 v;
        v[0] = (bf16)a0.x; v[1] = (bf16)a0.y; v[2] = (bf16)a0.z; v[3] = (bf16)a0.w;
        v[4] = (bf16)a1.x; v[5] = (bf16)a1.y; v[6] = (bf16)a1.z; v[7] = (bf16)a1.w;
        af[i] = v;
      }
#pragma unroll
      for (int j = 0; j < 4; j++)
        bfr[j] = *(const bf16x8*)&smemB[((wn * 4 + j) * 2 + t) * 512 + lane * 8];
#pragma unroll
      for (int i = 0; i < 4; i++)
#pragma unroll
        for (int j = 0; j < 4; j++)
          acc[i][j] = __builtin_amdgcn_mfma_f32_16x16x32_bf16(af[i], bfr[j], acc[i][j], 0, 0, 0);
    }
    __syncthreads();
  }
  bf16* Ob = out1 + (long)(b * 8 + s) * 2048 * 512;
#pragma unroll
  for (int i = 0; i < 4; i++) {
    int row = mt * 128 + wm * 64 + i * 16 + lq * 4;
#pragma unroll
    for (int j = 0; j < 4; j++) {
      int col = nt * 128 + wn * 64 + j * 16 + lr;
#pragma unroll
      for (int r = 0; r < 4; r++)
        Ob[(long)(row + r) * 512 + col] = f2bf(acc[i][j][r]);
    }
  }
}

// ---------------- stage 2: gated retrieval selection ----------------
// v_logits[r] = (Wvk @ q_v) . out[r]  (+ const that cancels in softmax)
__global__ __launch_bounds__(256) void k_stage2(const bf16* __restrict__ out1,
                                                const bf16* __restrict__ qkvq,
                                                const float* __restrict__ Wvk,
                                                float* __restrict__ vsout,
                                                bf16* __restrict__ out2) {
  __shared__ float so[8][8][64];   // [s][r][v]
  __shared__ float qvl[4][2][64];
  int b = blockIdx.x >> 11, n = blockIdx.x & 2047;
  int tid = threadIdx.x, w = tid >> 6, lane = tid & 63;

  float wr[64];  // Wvk row `lane`: Wvk[v=lane][h]
#pragma unroll
  for (int c = 0; c < 16; c++) {
    float4 t4 = *(const float4*)(Wvk + lane * 64 + c * 4);
    wr[c * 4 + 0] = t4.x; wr[c * 4 + 1] = t4.y;
    wr[c * 4 + 2] = t4.z; wr[c * 4 + 3] = t4.w;
  }
  for (int c = tid; c < 512; c += 256) {
    int s = c >> 6; int off = (c & 63) * 8;
    bf16x8 v = *(const bf16x8*)(out1 + ((long)(b * 8 + s) * 2048 + n) * 512 + off);
#pragma unroll
    for (int e = 0; e < 8; e++) so[s][(off + e) >> 6][(off + e) & 63] = (float)v[e];
  }
#pragma unroll
  for (int si = 0; si < 2; si++) {
    int s = w * 2 + si;
    qvl[w][si][lane] = (float)qkvq[(long)(b * 2048 + n) * 2048 + 1536 + s * 64 + lane];
  }
  __syncthreads();

#pragma unroll
  for (int si = 0; si < 2; si++) {
    int s = w * 2 + si;
    float qw = 0.f;  // qw[v=lane] = sum_h qv[h]*Wvk[v][h]
#pragma unroll
    for (int c = 0; c < 16; c++) {
      float4 q4 = *(const float4*)&qvl[w][si][c * 4];
      qw += q4.x * wr[c * 4 + 0] + q4.y * wr[c * 4 + 1] +
            q4.z * wr[c * 4 + 2] + q4.w * wr[c * 4 + 3];
    }
    float lg[8], sor[8];
#pragma unroll
    for (int r = 0; r < 8; r++) {
      sor[r] = so[s][r][lane];
      float p = sor[r] * qw;
      p += __shfl_xor(p, 1);  p += __shfl_xor(p, 2);  p += __shfl_xor(p, 4);
      p += __shfl_xor(p, 8);  p += __shfl_xor(p, 16); p += __shfl_xor(p, 32);
      lg[r] = p;
    }
    float mx = lg[0];
#pragma unroll
    for (int r = 1; r < 8; r++) mx = fmaxf(mx, lg[r]);
    float e[8], sum = 0.f;
#pragma unroll
    for (int r = 0; r < 8; r++) { e[r] = __expf(lg[r] - mx); sum += e[r]; }
    float rs = 1.f / sum;
    float myv = 0.f;
#pragma unroll
    for (int r = 0; r < 8; r++) myv = (lane == r) ? e[r] * rs : myv;
    if (lane < 8) vsout[((long)(b * 2048 + n) * 8 + s) * 8 + lane] = myv;
    float o2 = 0.f;
#pragma unroll
    for (int r = 0; r < 8; r++) o2 += e[r] * rs * sor[r];
    out2[(long)(b * 2048 + n) * 512 + s * 64 + lane] = f2bf(o2);
  }
}

// ---------------- launch ----------------
extern "C" void kernel_launch(void* const* d_in, const int* in_sizes, int n_in,
                              void* d_out, int out_size, void* d_ws, size_t ws_size,
                              hipStream_t stream) {
  const float* x   = (const float*)d_in[0];
  const float* Wq  = (const float*)d_in[1];  const float* bq  = (const float*)d_in[2];
  const float* Wk  = (const float*)d_in[3];  const float* bk  = (const float*)d_in[4];
  const float* Wv  = (const float*)d_in[5];  const float* bv  = (const float*)d_in[6];
  const float* Wvq = (const float*)d_in[7];  const float* bvq = (const float*)d_in[8];
  const float* Wvk = (const float*)d_in[9];  const float* bvk = (const float*)d_in[10];
  const float* Wo  = (const float*)d_in[11]; const float* bo  = (const float*)d_in[12];
  (void)bvk; (void)in_sizes; (void)n_in; (void)out_size; (void)ws_size;

  char* ws = (char*)d_ws;
  bf16*  qkvq  = (bf16*)(ws + 0);          // [8192][2048]  (Q|K|V|Qv), q/qv pre-scaled
  bf16*  xb    = (bf16*)(ws + 33554432);   // [8192][512]
  bf16*  wcatT = (bf16*)(ws + 41943040);   // [2048][512]
  bf16*  woT   = (bf16*)(ws + 44040192);   // [512][512]
  float* bcat  = (float*)(ws + 44564480);  // [2048]
  bf16*  vt    = (bf16*)(ws + 44572672);   // [4][512][2048]
  float* rinv  = (float*)(ws + 52961280);  // [4][8][2048]
  bf16*  out1  = (bf16*)(ws + 53223424);   // [4][8][2048][512]
  bf16*  out2  = (bf16*)(ws + 120332288);  // [8192][512]
  // total ws use: 128,720,896 B

  float* y  = (float*)d_out;
  float* sc = y + 4194304;     // [4][8][2048][2048]
  float* vs = y + 138412032;   // [4][2048][8][8]

  k_cvt_x<<<2048, 256, 0, stream>>>(x, xb);
  k_cvt_wcat<<<2048, 256, 0, stream>>>(Wq, bq, Wk, bk, Wv, bv, Wvq, bvq, wcatT, bcat);
  k_cvt_wo<<<512, 256, 0, stream>>>(Wo, woT);
  k_gemm<bf16><<<1024, 256, 0, stream>>>(xb, 512, wcatT, 512, qkvq, 2048, bcat, 512, 16);
  k_transpose_v<<<1024, 256, 0, stream>>>(qkvq, vt);
  k_rowsum<<<512, 256, 0, stream>>>(qkvq, rinv);
  k_pwrite<<<8192, 256, 0, stream>>>(qkvq, rinv, sc);
  k_pv<<<2048, 256, 0, stream>>>(sc, vt, out1);
  k_stage2<<<8192, 256, 0, stream>>>(out1, qkvq, Wvk, vs, out2);
  k_gemm<float><<<256, 256, 0, stream>>>(out2, 512, woT, 512, y, 512, bo, 512, 4);
}